// Round 2
// baseline (178.746 us; speedup 1.0000x reference)
//
#include <hip/hip_runtime.h>
#include <hip/hip_cooperative_groups.h>

namespace cg = cooperative_groups;

// BoundaryLoss: mean(sigmoid(logits) * EDT2D(target)), B=8, H=W=256.
//
// SINGLE cooperative kernel (1 dispatch; the timed window's floor is the
// harness's 256 MiB workspace poison fill at ~42 us, so dispatch-count and
// inter-dispatch gaps dominate everything else).
//   Phase 1: O(W) row 1D-distance via wave max/min scans -> dr2 (bit-exact
//            integer distances; empty row -> fl(1e12)).
//   grid.sync()
//   Phase 2: column EDT (the O(H^2 W) payload): strength-reduced
//            min_j (i-j)^2 + m_j = i^2 + min_j (j^2 + m_j - 2ij); q_j staged
//            in LDS, broadcast ds_read_b128 feeds 16 fma+min per float4.
//            + sigmoid weighting + per-block reduce -> partials.
//   grid.sync()
//   Phase 3: block 0 reduces 512 partials in the exact fp order of the
//            original final_reduce_kernel (absmax stays 0.0).

#define BIGF 1000000.0f
#define BIG2 (BIGF * BIGF)   // fp32 rounding of 1e12, same as ref's BIG*BIG
#define BIGI (1 << 20)

constexpr int B = 8;
constexpr int H = 256;
constexpr int W = 256;
constexpr int NPIX = B * H * W;   // 524288
constexpr int NBLK = 512;         // 2 blocks/CU -> trivially co-resident

__device__ __forceinline__ float block_reduce_sum_256(float v) {
    #pragma unroll
    for (int off = 32; off > 0; off >>= 1)
        v += __shfl_down(v, off, 64);
    __shared__ float s[4];
    const int lane = threadIdx.x & 63;
    const int wid  = threadIdx.x >> 6;
    if (lane == 0) s[wid] = v;
    __syncthreads();
    if (wid == 0) {
        v = (lane < 4) ? s[lane] : 0.0f;
        v += __shfl_down(v, 2, 64);
        v += __shfl_down(v, 1, 64);
    }
    return v;  // valid on thread 0
}

// 16 candidates (4 outputs x 4 j's) per LDS float4.
__device__ __forceinline__ void upd16(const float4 m, float j0,
                                      float n0, float n1, float n2, float n3,
                                      float& b0, float& b1, float& b2, float& b3) {
    const float j1 = j0 + 1.0f, j2 = j0 + 2.0f, j3 = j0 + 3.0f;
    {
        const float c0 = fmaf(n0, j0, m.x), c1 = fmaf(n0, j1, m.y);
        const float c2 = fmaf(n0, j2, m.z), c3 = fmaf(n0, j3, m.w);
        b0 = fminf(b0, fminf(fminf(c0, c1), fminf(c2, c3)));
    }
    {
        const float c0 = fmaf(n1, j0, m.x), c1 = fmaf(n1, j1, m.y);
        const float c2 = fmaf(n1, j2, m.z), c3 = fmaf(n1, j3, m.w);
        b1 = fminf(b1, fminf(fminf(c0, c1), fminf(c2, c3)));
    }
    {
        const float c0 = fmaf(n2, j0, m.x), c1 = fmaf(n2, j1, m.y);
        const float c2 = fmaf(n2, j2, m.z), c3 = fmaf(n2, j3, m.w);
        b2 = fminf(b2, fminf(fminf(c0, c1), fminf(c2, c3)));
    }
    {
        const float c0 = fmaf(n3, j0, m.x), c1 = fmaf(n3, j1, m.y);
        const float c2 = fmaf(n3, j2, m.z), c3 = fmaf(n3, j3, m.w);
        b3 = fminf(b3, fminf(fminf(c0, c1), fminf(c2, c3)));
    }
}

__global__ __launch_bounds__(256, 2) void fused_kernel(
        const float* __restrict__ logits, const int* __restrict__ target,
        float* __restrict__ dr2, float* __restrict__ partials,
        float* __restrict__ out) {
    cg::grid_group grid = cg::this_grid();
    const int t    = threadIdx.x;
    const int lane = t & 63;
    const int wv   = t >> 6;

    // ================= Phase 1: row squared-distances (wave scans) ========
    // Block handles rows 4*blk .. 4*blk+3; wave wv -> one row; lane L owns
    // pixels 4L..4L+3.
    {
        const int row = (blockIdx.x << 2) + wv;
        const int4 tv = *(const int4*)(target + row * W + (lane << 2));
        const int i0 = lane << 2;

        // ---- left scan: nearest fg index <= p ----
        int lastL = -1;
        if (tv.x > 0) lastL = i0;
        if (tv.y > 0) lastL = i0 + 1;
        if (tv.z > 0) lastL = i0 + 2;
        if (tv.w > 0) lastL = i0 + 3;
        int incl = lastL;
        #pragma unroll
        for (int off = 1; off < 64; off <<= 1) {
            const int x = __shfl_up(incl, off, 64);
            if (lane >= off) incl = max(incl, x);
        }
        int runL = __shfl_up(incl, 1, 64);
        if (lane == 0) runL = -1;            // exclusive prefix

        if (tv.x > 0) runL = i0;
        const int dl0 = (runL >= 0) ? (i0     - runL) : BIGI;
        if (tv.y > 0) runL = i0 + 1;
        const int dl1 = (runL >= 0) ? (i0 + 1 - runL) : BIGI;
        if (tv.z > 0) runL = i0 + 2;
        const int dl2 = (runL >= 0) ? (i0 + 2 - runL) : BIGI;
        if (tv.w > 0) runL = i0 + 3;
        const int dl3 = (runL >= 0) ? (i0 + 3 - runL) : BIGI;

        // ---- right scan: nearest fg index >= p ----
        int nextR = BIGI;
        if (tv.w > 0) nextR = i0 + 3;
        if (tv.z > 0) nextR = i0 + 2;
        if (tv.y > 0) nextR = i0 + 1;
        if (tv.x > 0) nextR = i0;
        int inclR = nextR;
        #pragma unroll
        for (int off = 1; off < 64; off <<= 1) {
            const int x = __shfl_down(inclR, off, 64);
            if (lane < 64 - off) inclR = min(inclR, x);
        }
        int runR = __shfl_down(inclR, 1, 64);
        if (lane == 63) runR = BIGI;         // exclusive suffix

        if (tv.w > 0) runR = i0 + 3;
        const int dR3 = runR - (i0 + 3);
        if (tv.z > 0) runR = i0 + 2;
        const int dR2v = runR - (i0 + 2);
        if (tv.y > 0) runR = i0 + 1;
        const int dR1 = runR - (i0 + 1);
        if (tv.x > 0) runR = i0;
        const int dR0 = runR - i0;

        // ---- combine, square (exact ints < 2^24), coalesced float4 store --
        const int d0 = min(dl0, dR0), d1 = min(dl1, dR1);
        const int d2 = min(dl2, dR2v), d3 = min(dl3, dR3);
        const float f0 = (float)d0, f1 = (float)d1;
        const float f2 = (float)d2, f3 = (float)d3;
        float4 o;
        o.x = (d0 > 255) ? BIG2 : f0 * f0;
        o.y = (d1 > 255) ? BIG2 : f1 * f1;
        o.z = (d2 > 255) ? BIG2 : f2 * f2;
        o.w = (d3 > 255) ? BIG2 : f3 * f3;
        *(float4*)(dr2 + row * W + (lane << 2)) = o;
    }

    grid.sync();

    // ================= Phase 2: column EDT + sigmoid + block reduce =======
    // Block -> (batch b, columns w0..w0+3); wave wv -> one column.
    __shared__ float s_q[4][256];
    {
        const int b  = blockIdx.x >> 6;
        const int w0 = (blockIdx.x & 63) << 2;

        // stage q_j = j^2 + dr2[j][w0+c]; thread t handles j = t
        const float4 v  = *(const float4*)(dr2 + (b * H + t) * W + w0);
        const float fj  = (float)t;
        const float fj2 = fj * fj;              // exact (< 2^24)
        s_q[0][t] = fj2 + v.x;
        s_q[1][t] = fj2 + v.y;
        s_q[2][t] = fj2 + v.z;
        s_q[3][t] = fj2 + v.w;
        __syncthreads();

        const float i0f = (float)lane,         i1f = (float)(lane + 64);
        const float i2f = (float)(lane + 128), i3f = (float)(lane + 192);
        const float n0 = -2.0f * i0f, n1 = -2.0f * i1f;
        const float n2 = -2.0f * i2f, n3 = -2.0f * i3f;
        float b0 = 4e12f, b1 = 4e12f, b2 = 4e12f, b3 = 4e12f;

        float fjv = 0.0f;
        #pragma unroll 4
        for (int jv = 0; jv < 64; ++jv, fjv += 4.0f) {
            const float4 m = *(const float4*)&s_q[wv][jv << 2];
            upd16(m, fjv, n0, n1, n2, n3, b0, b1, b2, b3);
        }

        const int wcol = w0 + wv;
        const int base = (b * H + lane) * W + wcol;
        float acc;
        {
            const float dist = sqrtf(fmaf(i0f, i0f, b0));
            const float x = logits[base];
            acc = dist / (1.0f + expf(-x));
        }
        {
            const float dist = sqrtf(fmaf(i1f, i1f, b1));
            const float x = logits[base + 64 * W];
            acc += dist / (1.0f + expf(-x));
        }
        {
            const float dist = sqrtf(fmaf(i2f, i2f, b2));
            const float x = logits[base + 128 * W];
            acc += dist / (1.0f + expf(-x));
        }
        {
            const float dist = sqrtf(fmaf(i3f, i3f, b3));
            const float x = logits[base + 192 * W];
            acc += dist / (1.0f + expf(-x));
        }

        const float s = block_reduce_sum_256(acc);
        if (t == 0) partials[blockIdx.x] = s;
    }

    grid.sync();

    // ================= Phase 3: block 0 final reduce (deterministic) ======
    if (blockIdx.x == 0) {
        // exact same fp order as the original final_reduce_kernel:
        // v = (0 + partials[t]) + partials[t+256], then the same block tree.
        float fv = partials[t] + partials[t + 256];
        const float tot = block_reduce_sum_256(fv);
        if (t == 0) out[0] = tot * (1.0f / (float)NPIX);
    }
}

extern "C" void kernel_launch(void* const* d_in, const int* in_sizes, int n_in,
                              void* d_out, int out_size, void* d_ws, size_t ws_size,
                              hipStream_t stream) {
    const float* logits = (const float*)d_in[0];
    const int*   target = (const int*)d_in[1];

    float* dr2      = (float*)d_ws;          // NPIX floats (2 MB)
    float* partials = dr2 + NPIX;            // 512 floats
    float* outp     = (float*)d_out;

    void* args[] = {(void*)&logits, (void*)&target, (void*)&dr2,
                    (void*)&partials, (void*)&outp};
    hipLaunchCooperativeKernel((const void*)fused_kernel, dim3(NBLK), dim3(256),
                               args, 0, stream);
}

// Round 3
// 70.401 us; speedup vs baseline: 2.5390x; 2.5390x over previous
//
#include <hip/hip_runtime.h>

// BoundaryLoss: mean(sigmoid(logits) * EDT2D(target)), B=8, H=W=256.
//
// Structure: 3 dispatches (row pass, column pass, final reduce).
// Round-2 evidence: any in-kernel cross-block dependency (grid.sync or
// threadfence+ticket) pays a device-scope L2 writeback/invalidate on the
// 8-XCD gfx950 (~50 us per grid sync!) -- separate dispatches amortize that
// coherence flush into the launch machinery and are strictly cheaper.
// The timed-window floor is the harness's 256 MiB workspace poison fill
// (~42 us @ 6.4 TB/s) + ~5 us/dispatch gap; only the kernel bodies are ours.
//
// Pass 1: O(W) row 1D-distance via wave max/min scans (bit-exact integer
//         distances; empty row -> fl(1e12) = BIG2, same as ref).
// Pass 2: column EDT, the O(H^2 W) payload: strength-reduced
//         min_j (i-j)^2 + m_j = i^2 + min_j (j^2 + m_j - 2ij); q_j staged in
//         LDS, broadcast ds_read_b128 feeds 16 fma+min per float4.
// Pass 3: 512-element deterministic reduce (exact ref fp order).

#define BIGF 1000000.0f
#define BIG2 (BIGF * BIGF)   // fp32 rounding of 1e12, same as ref's BIG*BIG
#define BIGI (1 << 20)

constexpr int B = 8;
constexpr int H = 256;
constexpr int W = 256;
constexpr int NPIX = B * H * W;   // 524288

__device__ __forceinline__ float block_reduce_sum_256(float v) {
    #pragma unroll
    for (int off = 32; off > 0; off >>= 1)
        v += __shfl_down(v, off, 64);
    __shared__ float s[4];
    const int lane = threadIdx.x & 63;
    const int wid  = threadIdx.x >> 6;
    if (lane == 0) s[wid] = v;
    __syncthreads();
    if (wid == 0) {
        v = (lane < 4) ? s[lane] : 0.0f;
        v += __shfl_down(v, 2, 64);
        v += __shfl_down(v, 1, 64);
    }
    return v;  // valid on thread 0
}

// 16 candidates (4 outputs x 4 j's) per LDS float4.
__device__ __forceinline__ void upd16(const float4 m, float j0,
                                      float n0, float n1, float n2, float n3,
                                      float& b0, float& b1, float& b2, float& b3) {
    const float j1 = j0 + 1.0f, j2 = j0 + 2.0f, j3 = j0 + 3.0f;
    {
        const float c0 = fmaf(n0, j0, m.x), c1 = fmaf(n0, j1, m.y);
        const float c2 = fmaf(n0, j2, m.z), c3 = fmaf(n0, j3, m.w);
        b0 = fminf(b0, fminf(fminf(c0, c1), fminf(c2, c3)));
    }
    {
        const float c0 = fmaf(n1, j0, m.x), c1 = fmaf(n1, j1, m.y);
        const float c2 = fmaf(n1, j2, m.z), c3 = fmaf(n1, j3, m.w);
        b1 = fminf(b1, fminf(fminf(c0, c1), fminf(c2, c3)));
    }
    {
        const float c0 = fmaf(n2, j0, m.x), c1 = fmaf(n2, j1, m.y);
        const float c2 = fmaf(n2, j2, m.z), c3 = fmaf(n2, j3, m.w);
        b2 = fminf(b2, fminf(fminf(c0, c1), fminf(c2, c3)));
    }
    {
        const float c0 = fmaf(n3, j0, m.x), c1 = fmaf(n3, j1, m.y);
        const float c2 = fmaf(n3, j2, m.z), c3 = fmaf(n3, j3, m.w);
        b3 = fminf(b3, fminf(fminf(c0, c1), fminf(c2, c3)));
    }
}

// Pass 1: row squared-distances via wave scans. 512 blocks x 256 thr;
// wave wv handles row blk*4+wv, lane L owns pixels 4L..4L+3.
__global__ __launch_bounds__(256) void row_dist_kernel(
        const int* __restrict__ target, float* __restrict__ dr2) {
    const int lane = threadIdx.x & 63;
    const int wv   = threadIdx.x >> 6;
    const int row  = (blockIdx.x << 2) + wv;

    const int4 tv = *(const int4*)(target + row * W + (lane << 2));
    const int i0 = lane << 2;

    // ---- left scan: nearest fg index <= p ----
    int lastL = -1;                      // lane-local last fg idx
    if (tv.x > 0) lastL = i0;
    if (tv.y > 0) lastL = i0 + 1;
    if (tv.z > 0) lastL = i0 + 2;
    if (tv.w > 0) lastL = i0 + 3;
    int incl = lastL;
    #pragma unroll
    for (int off = 1; off < 64; off <<= 1) {
        const int x = __shfl_up(incl, off, 64);
        if (lane >= off) incl = max(incl, x);
    }
    int runL = __shfl_up(incl, 1, 64);
    if (lane == 0) runL = -1;            // exclusive prefix

    if (tv.x > 0) runL = i0;
    const int dl0 = (runL >= 0) ? (i0     - runL) : BIGI;
    if (tv.y > 0) runL = i0 + 1;
    const int dl1 = (runL >= 0) ? (i0 + 1 - runL) : BIGI;
    if (tv.z > 0) runL = i0 + 2;
    const int dl2 = (runL >= 0) ? (i0 + 2 - runL) : BIGI;
    if (tv.w > 0) runL = i0 + 3;
    const int dl3 = (runL >= 0) ? (i0 + 3 - runL) : BIGI;

    // ---- right scan: nearest fg index >= p ----
    int nextR = BIGI;                    // lane-local first fg idx
    if (tv.w > 0) nextR = i0 + 3;
    if (tv.z > 0) nextR = i0 + 2;
    if (tv.y > 0) nextR = i0 + 1;
    if (tv.x > 0) nextR = i0;
    int inclR = nextR;
    #pragma unroll
    for (int off = 1; off < 64; off <<= 1) {
        const int x = __shfl_down(inclR, off, 64);
        if (lane < 64 - off) inclR = min(inclR, x);
    }
    int runR = __shfl_down(inclR, 1, 64);
    if (lane == 63) runR = BIGI;         // exclusive suffix

    if (tv.w > 0) runR = i0 + 3;
    const int dR3 = runR - (i0 + 3);
    if (tv.z > 0) runR = i0 + 2;
    const int dR2v = runR - (i0 + 2);
    if (tv.y > 0) runR = i0 + 1;
    const int dR1 = runR - (i0 + 1);
    if (tv.x > 0) runR = i0;
    const int dR0 = runR - i0;

    // ---- combine, square (exact ints < 2^24), coalesced float4 store ----
    const int d0 = min(dl0, dR0), d1 = min(dl1, dR1);
    const int d2 = min(dl2, dR2v), d3 = min(dl3, dR3);
    const float f0 = (float)d0, f1 = (float)d1, f2 = (float)d2, f3 = (float)d3;
    float4 o;
    o.x = (d0 > 255) ? BIG2 : f0 * f0;
    o.y = (d1 > 255) ? BIG2 : f1 * f1;
    o.z = (d2 > 255) ? BIG2 : f2 * f2;
    o.w = (d3 > 255) ? BIG2 : f3 * f3;
    *(float4*)(dr2 + row * W + (lane << 2)) = o;
}

// Pass 2: column EDT + sqrt + sigmoid + per-block reduce.
// 512 blocks x 256 thr; block -> (batch b, columns w0..w0+3); wave c -> col.
__global__ __launch_bounds__(256) void col_pass_kernel(
        const float* __restrict__ logits, const float* __restrict__ dr2,
        float* __restrict__ partials) {
    __shared__ float s_q[4][256];
    const int t  = threadIdx.x;
    const int b  = blockIdx.x >> 6;
    const int w0 = (blockIdx.x & 63) << 2;

    // stage q_j = j^2 + dr2[j][w0+c]; thread t handles j = t (float4 per thread)
    const float4 v  = *(const float4*)(dr2 + (b * H + t) * W + w0);
    const float fj  = (float)t;
    const float fj2 = fj * fj;              // exact (< 2^24)
    s_q[0][t] = fj2 + v.x;
    s_q[1][t] = fj2 + v.y;
    s_q[2][t] = fj2 + v.z;
    s_q[3][t] = fj2 + v.w;
    __syncthreads();

    const int lane = t & 63;
    const int wv   = t >> 6;
    const float i0f = (float)lane,         i1f = (float)(lane + 64);
    const float i2f = (float)(lane + 128), i3f = (float)(lane + 192);
    const float n0 = -2.0f * i0f, n1 = -2.0f * i1f;
    const float n2 = -2.0f * i2f, n3 = -2.0f * i3f;
    float b0 = 4e12f, b1 = 4e12f, b2 = 4e12f, b3 = 4e12f;

    float fjv = 0.0f;
    #pragma unroll 4
    for (int jv = 0; jv < 64; ++jv, fjv += 4.0f) {
        const float4 m = *(const float4*)&s_q[wv][jv << 2];
        upd16(m, fjv, n0, n1, n2, n3, b0, b1, b2, b3);
    }

    const int wcol = w0 + wv;
    const int base = (b * H + lane) * W + wcol;
    float acc;
    {
        const float dist = sqrtf(fmaf(i0f, i0f, b0));
        const float x = logits[base];
        acc = dist / (1.0f + expf(-x));
    }
    {
        const float dist = sqrtf(fmaf(i1f, i1f, b1));
        const float x = logits[base + 64 * W];
        acc += dist / (1.0f + expf(-x));
    }
    {
        const float dist = sqrtf(fmaf(i2f, i2f, b2));
        const float x = logits[base + 128 * W];
        acc += dist / (1.0f + expf(-x));
    }
    {
        const float dist = sqrtf(fmaf(i3f, i3f, b3));
        const float x = logits[base + 192 * W];
        acc += dist / (1.0f + expf(-x));
    }

    const float s = block_reduce_sum_256(acc);
    if (t == 0) partials[blockIdx.x] = s;
}

__global__ __launch_bounds__(256) void final_reduce_kernel(
        const float* __restrict__ partials, float* __restrict__ out,
        int n, float scale) {
    float v = 0.0f;
    for (int idx = threadIdx.x; idx < n; idx += 256)
        v += partials[idx];
    v = block_reduce_sum_256(v);
    if (threadIdx.x == 0) out[0] = v * scale;
}

extern "C" void kernel_launch(void* const* d_in, const int* in_sizes, int n_in,
                              void* d_out, int out_size, void* d_ws, size_t ws_size,
                              hipStream_t stream) {
    const float* logits = (const float*)d_in[0];
    const int*   target = (const int*)d_in[1];

    float* dr2      = (float*)d_ws;     // NPIX floats (2 MB)
    float* partials = dr2 + NPIX;       // 512 floats

    row_dist_kernel<<<B * H / 4, 256, 0, stream>>>(target, dr2);
    col_pass_kernel<<<B * W / 4, 256, 0, stream>>>(logits, dr2, partials);
    final_reduce_kernel<<<1, 256, 0, stream>>>(partials, (float*)d_out,
                                               B * W / 4, 1.0f / (float)NPIX);
}